// Round 2
// baseline (120.063 us; speedup 1.0000x reference)
//
#include <hip/hip_runtime.h>
#include <hip/hip_bf16.h>
#include <math.h>

#define NN    2048
#define ODIM  32
#define IDIM  128
#define NEGINF (-9.0e15f)
#define LEAK   0.05f
#define LNEPS  1e-6f
#define NCHEB  14          // degree; NCHEB+1 coefficients
#define ROWS   4           // rows per block in main kernel

// ws layout (floats)
#define Z_OFF   16
#define SRC_OFF (Z_OFF + NN*ODIM)
#define DST_OFF (SRC_OFF + NN)

// ---------------------------------------------------------------------------
// Kernel S: Chebyshev coefficients of g(ts) = sum_k ae_k*sin((te-ts)*f_k)
//                                           + ao_k*cos((te-ts)*f_k), ts in [0,1]
// Chebyshev-Lobatto nodes, DCT-I, computed in f64. 15 floats -> ws[0..14].
// ---------------------------------------------------------------------------
__global__ __launch_bounds__(512) void k_setup(const float* __restrict__ a,
                                               const float* __restrict__ bfreq,
                                               const int* __restrict__ time_end,
                                               float* __restrict__ ws)
{
    __shared__ double g[NCHEB + 1];
    const int t = threadIdx.x;
    const double te = (double)(*time_end);

    if (t < (NCHEB + 1) * 32) {
        const int j = t >> 5, k = t & 31;
        double u   = cos(M_PI * (double)j / (double)NCHEB);   // node in [-1,1]
        double tsv = 0.5 * (u + 1.0);                          // ts in [0,1]
        double dt  = te - tsv;
        double m   = dt * (double)bfreq[k];
        double term = (double)a[2 * k] * sin(m) + (double)a[2 * k + 1] * cos(m);
        #pragma unroll
        for (int off = 16; off >= 1; off >>= 1)
            term += __shfl_xor(term, off, 32);
        if (k == 0) g[j] = term;
    }
    __syncthreads();
    if (t <= NCHEB) {
        double sl = 0.0;
        for (int j = 0; j <= NCHEB; ++j) {
            double w = (j == 0 || j == NCHEB) ? 0.5 : 1.0;
            sl += w * g[j] * cos(M_PI * (double)(t * j) / (double)NCHEB);
        }
        double c = ((t == 0 || t == NCHEB) ? (1.0 / NCHEB) : (2.0 / NCHEB)) * sl;
        ws[t] = (float)c;   // plain-sum coefficients: p(u) = sum c_k T_k(u)
    }
}

// ---------------------------------------------------------------------------
// Kernel Z: z = ini @ W (f32), src = z@a[:32], dst = z@a[32:]
// 8 rows per block; thread (r,k) computes z[row][k].
// ---------------------------------------------------------------------------
__global__ __launch_bounds__(256) void k_z(const float* __restrict__ ini,
                                           const float* __restrict__ a,
                                           const float* __restrict__ W,
                                           float* __restrict__ ws)
{
    __shared__ float Wl[IDIM * ODIM];   // 16 KB
    __shared__ float inil[8 * IDIM];    //  4 KB
    const int tid  = threadIdx.x;
    const int row0 = blockIdx.x * 8;

    // stage W (4096 f32) and 8 ini rows (1024 f32), vectorized
    {
        const float4* Wv = reinterpret_cast<const float4*>(W);
        float4* Wlv = reinterpret_cast<float4*>(Wl);
        #pragma unroll
        for (int i = 0; i < 4; ++i) Wlv[tid + i * 256] = Wv[tid + i * 256];
        const float4* iv = reinterpret_cast<const float4*>(ini + row0 * IDIM);
        reinterpret_cast<float4*>(inil)[tid] = iv[tid];
    }
    __syncthreads();

    const int r = tid >> 5, k = tid & 31;
    float acc = 0.f;
    #pragma unroll 8
    for (int c = 0; c < IDIM; ++c)
        acc = fmaf(inil[r * IDIM + c], Wl[c * ODIM + k], acc);

    float* z   = ws + Z_OFF;
    float* src = ws + SRC_OFF;
    float* dst = ws + DST_OFF;
    z[(row0 + r) * ODIM + k] = acc;

    float sv = acc * a[k];
    float dv = acc * a[32 + k];
    #pragma unroll
    for (int off = 16; off >= 1; off >>= 1) {
        sv += __shfl_xor(sv, off, 32);
        dv += __shfl_xor(dv, off, 32);
    }
    if (k == 0) { src[row0 + r] = sv; dst[row0 + r] = dv; }
}

// Clenshaw evaluation of the Chebyshev interpolant (coeffs in registers)
__device__ __forceinline__ float cheb_eval(const float cc[NCHEB + 1], float ts)
{
    float u  = fmaf(2.0f, ts, -1.0f);
    float tu = u + u;
    float b1 = 0.f, b2 = 0.f;
    #pragma unroll
    for (int k = NCHEB; k >= 1; --k) {
        float b = fmaf(tu, b1, cc[k] - b2);
        b2 = b1; b1 = b;
    }
    return fmaf(u, b1, cc[0] - b2);
}

// ---------------------------------------------------------------------------
// Kernel M: logits -> softmax -> att@z + z -> LayerNorm.  4 rows per block.
// ---------------------------------------------------------------------------
__global__ __launch_bounds__(256) void k_main(const int* __restrict__ adj,
                                              const float* __restrict__ tsm,
                                              const float* __restrict__ ws,
                                              const float* __restrict__ gam,
                                              const float* __restrict__ bet,
                                              float* __restrict__ out)
{
    __shared__ float lg[ROWS][NN];            // 32 KB logits -> probabilities
    __shared__ float zi[ROWS][ODIM];
    __shared__ float wred[4][ROWS];
    __shared__ float part[8][ROWS][ODIM];     // 4 KB

    const float* cw  = ws;
    const float* z   = ws + Z_OFF;
    const float* src = ws + SRC_OFF;
    const float* dst = ws + DST_OFF;

    const int tid  = threadIdx.x;
    const int row0 = blockIdx.x * ROWS;

    float cc[NCHEB + 1];
    #pragma unroll
    for (int k = 0; k <= NCHEB; ++k) cc[k] = cw[k];

    if (tid < ROWS * ODIM) zi[tid >> 5][tid & 31] = z[row0 * ODIM + tid];

    float srcv[ROWS];
    #pragma unroll
    for (int r = 0; r < ROWS; ++r) srcv[r] = src[row0 + r];

    // ---- phase 1: logits + per-thread row max -----------------------------
    float rmax[ROWS];
    #pragma unroll
    for (int r = 0; r < ROWS; ++r) rmax[r] = NEGINF;

    #pragma unroll
    for (int jj = 0; jj < 2; ++jj) {
        const int j = jj * 1024 + tid * 4;
        float4 d4 = *reinterpret_cast<const float4*>(dst + j);
        const float dv[4] = {d4.x, d4.y, d4.z, d4.w};
        #pragma unroll
        for (int r = 0; r < ROWS; ++r) {
            const int base = (row0 + r) * NN + j;
            int4   a4 = *reinterpret_cast<const int4*>(adj + base);
            float4 t4 = *reinterpret_cast<const float4*>(tsm + base);
            const int   av[4] = {a4.x, a4.y, a4.z, a4.w};
            const float tv[4] = {t4.x, t4.y, t4.z, t4.w};
            float e[4];
            #pragma unroll
            for (int q = 0; q < 4; ++q) {
                float ev = srcv[r] + dv[q] + cheb_eval(cc, tv[q]);
                ev = ev > 0.f ? ev : LEAK * ev;          // LeakyReLU pre-mask
                ev = (av[q] > 0) ? ev : NEGINF;
                e[q] = ev;
                rmax[r] = fmaxf(rmax[r], ev);
            }
            *reinterpret_cast<float4*>(&lg[r][j]) = make_float4(e[0], e[1], e[2], e[3]);
        }
    }

    // ---- row max reduction ------------------------------------------------
    #pragma unroll
    for (int r = 0; r < ROWS; ++r) {
        float v = rmax[r];
        #pragma unroll
        for (int off = 32; off >= 1; off >>= 1) v = fmaxf(v, __shfl_xor(v, off, 64));
        rmax[r] = v;
    }
    const int wid = tid >> 6;
    if ((tid & 63) == 0) {
        #pragma unroll
        for (int r = 0; r < ROWS; ++r) wred[wid][r] = rmax[r];
    }
    __syncthreads();
    float m[ROWS];
    #pragma unroll
    for (int r = 0; r < ROWS; ++r)
        m[r] = fmaxf(fmaxf(wred[0][r], wred[1][r]), fmaxf(wred[2][r], wred[3][r]));

    // ---- phase 1b: p = exp(logit - m), row sums ---------------------------
    float rs[ROWS] = {0.f, 0.f, 0.f, 0.f};
    #pragma unroll
    for (int jj = 0; jj < 2; ++jj) {
        const int j = jj * 1024 + tid * 4;
        #pragma unroll
        for (int r = 0; r < ROWS; ++r) {
            float4 v = *reinterpret_cast<float4*>(&lg[r][j]);
            float p0 = __expf(v.x - m[r]);
            float p1 = __expf(v.y - m[r]);
            float p2 = __expf(v.z - m[r]);
            float p3 = __expf(v.w - m[r]);
            rs[r] += (p0 + p1) + (p2 + p3);
            *reinterpret_cast<float4*>(&lg[r][j]) = make_float4(p0, p1, p2, p3);
        }
    }
    __syncthreads();   // wred(max) reads done; lg writes visible for phase 2
    #pragma unroll
    for (int r = 0; r < ROWS; ++r) {
        float v = rs[r];
        #pragma unroll
        for (int off = 32; off >= 1; off >>= 1) v += __shfl_xor(v, off, 64);
        rs[r] = v;
    }
    if ((tid & 63) == 0) {
        #pragma unroll
        for (int r = 0; r < ROWS; ++r) wred[wid][r] = rs[r];
    }
    __syncthreads();
    float s[ROWS];
    #pragma unroll
    for (int r = 0; r < ROWS; ++r)
        s[r] = (wred[0][r] + wred[1][r]) + (wred[2][r] + wred[3][r]);

    // ---- phase 2: acc[r][k] = sum_j p[r][j] * z[j][k] ---------------------
    const int k = tid & 31, g = tid >> 5;
    float acc[ROWS] = {0.f, 0.f, 0.f, 0.f};
    #pragma unroll 4
    for (int jj = 0; jj < NN / 8; ++jj) {
        const int j = (jj << 3) | g;
        float zv = z[j * ODIM + k];
        #pragma unroll
        for (int r = 0; r < ROWS; ++r) acc[r] = fmaf(lg[r][j], zv, acc[r]);
    }
    #pragma unroll
    for (int r = 0; r < ROWS; ++r) part[g][r][k] = acc[r];
    __syncthreads();

    // ---- epilogue: temp = att@z + z, LayerNorm ----------------------------
    if (tid < ROWS * ODIM) {
        const int r = tid >> 5, kk = tid & 31;
        float tot = 0.f;
        #pragma unroll
        for (int gg = 0; gg < 8; ++gg) tot += part[gg][r][kk];
        float temp = tot / s[r] + zi[r][kk];

        float mu = temp;
        #pragma unroll
        for (int off = 16; off >= 1; off >>= 1) mu += __shfl_xor(mu, off, 32);
        mu *= (1.0f / 32.0f);
        float d = temp - mu;
        float v2 = d * d;
        #pragma unroll
        for (int off = 16; off >= 1; off >>= 1) v2 += __shfl_xor(v2, off, 32);
        v2 *= (1.0f / 32.0f);
        float y = d * rsqrtf(v2 + LNEPS) * gam[kk] + bet[kk];
        out[(row0 + r) * ODIM + kk] = y;
    }
}

// ---------------------------------------------------------------------------
extern "C" void kernel_launch(void* const* d_in, const int* in_sizes, int n_in,
                              void* d_out, int out_size, void* d_ws, size_t ws_size,
                              hipStream_t stream)
{
    const float* ini = (const float*)d_in[0];
    const int*   adj = (const int*)  d_in[1];
    const float* tsm = (const float*)d_in[2];
    const float* a   = (const float*)d_in[3];
    const int*   te  = (const int*)  d_in[4];
    const float* W   = (const float*)d_in[5];
    const float* bfq = (const float*)d_in[6];
    const float* gam = (const float*)d_in[7];
    const float* bet = (const float*)d_in[8];
    float* ws  = (float*)d_ws;
    float* out = (float*)d_out;

    k_setup<<<1, 512, 0, stream>>>(a, bfq, te, ws);
    k_z<<<NN / 8, 256, 0, stream>>>(ini, a, W, ws);
    k_main<<<NN / ROWS, 256, 0, stream>>>(adj, tsm, ws, gam, bet, out);
}

// Round 3
// 105.376 us; speedup vs baseline: 1.1394x; 1.1394x over previous
//
#include <hip/hip_runtime.h>
#include <hip/hip_bf16.h>
#include <math.h>

#define NN    2048
#define ODIM  32
#define IDIM  128
#define NEGINF (-9.0e15f)
#define LEAK   0.05f
#define LNEPS  1e-6f
#define NCHEB  10          // degree; NCHEB+1 coefficients
#define ROWS   4           // rows per block in main kernel

// ws layout (floats)
#define Z_OFF   16
#define SRC_OFF (Z_OFF + NN*ODIM)
#define DST_OFF (SRC_OFF + NN)

// ---------------------------------------------------------------------------
// Kernel Z: z = ini @ W, src = z@a[:32], dst = z@a[32:].
// Block 0 additionally computes the Chebyshev coefficients of
//   g(ts) = sum_k a[2k]*sin((te-ts)*f_k) + a[2k+1]*cos((te-ts)*f_k), ts in [0,1]
// in f32 (error ~1e-6, far below the 7.4e-2 threshold; kills the f64-libm
// single-block kernel that was a prime suspect for the 120us total).
// ---------------------------------------------------------------------------
__global__ __launch_bounds__(256) void k_z(const float* __restrict__ ini,
                                           const float* __restrict__ a,
                                           const float* __restrict__ W,
                                           const float* __restrict__ bfreq,
                                           const int* __restrict__ time_end,
                                           float* __restrict__ ws)
{
    __shared__ float Wt[ODIM * 132];     // W transposed [k][c], pad 132 (16B-aligned rows)
    __shared__ float inil[8 * IDIM];     // 8 ini rows
    __shared__ float gnode[NCHEB + 1];

    const int tid  = threadIdx.x;
    const int row0 = blockIdx.x * 8;

    if (blockIdx.x == 0) {
        const float te = (float)(*time_end);
        #pragma unroll
        for (int pass = 0; pass < 2; ++pass) {
            const int idx = tid + pass * 256;
            const int j = idx >> 5, k = idx & 31;
            float term = 0.f;
            if (idx < (NCHEB + 1) * 32) {
                float u   = cosf((float)M_PI * (float)j / (float)NCHEB);
                float tsv = 0.5f * (u + 1.0f);
                float mm  = (te - tsv) * bfreq[k];
                term = a[2 * k] * sinf(mm) + a[2 * k + 1] * cosf(mm);
            }
            #pragma unroll
            for (int off = 16; off >= 1; off >>= 1)
                term += __shfl_xor(term, off, 32);
            if (k == 0 && idx < (NCHEB + 1) * 32) gnode[j] = term;
        }
        __syncthreads();
        if (tid <= NCHEB) {
            float sl = 0.f;
            for (int j = 0; j <= NCHEB; ++j) {
                float w = (j == 0 || j == NCHEB) ? 0.5f : 1.0f;
                sl += w * gnode[j] * cosf((float)M_PI * (float)(tid * j) / (float)NCHEB);
            }
            ws[tid] = ((tid == 0 || tid == NCHEB) ? (1.0f / NCHEB) : (2.0f / NCHEB)) * sl;
        }
    }

    // ---- stage W transposed (float4 global loads) + 8 ini rows ------------
    {
        const float4* Wv = reinterpret_cast<const float4*>(W);   // [c][k/4]
        #pragma unroll
        for (int i = 0; i < 4; ++i) {
            const int idx = tid + i * 256;          // 1024 float4 = 4096 f32
            const int c = idx >> 3, k4 = (idx & 7) * 4;
            float4 v = Wv[idx];
            Wt[(k4 + 0) * 132 + c] = v.x;
            Wt[(k4 + 1) * 132 + c] = v.y;
            Wt[(k4 + 2) * 132 + c] = v.z;
            Wt[(k4 + 3) * 132 + c] = v.w;
        }
        const float4* iv = reinterpret_cast<const float4*>(ini + row0 * IDIM);
        reinterpret_cast<float4*>(inil)[tid] = iv[tid];
    }
    __syncthreads();

    const int r = tid >> 5, k = tid & 31;
    float acc = 0.f;
    #pragma unroll
    for (int c = 0; c < IDIM; c += 4) {
        float4 wv = *reinterpret_cast<const float4*>(&Wt[k * 132 + c]);
        float4 xv = *reinterpret_cast<const float4*>(&inil[r * IDIM + c]);
        acc = fmaf(xv.x, wv.x, acc);
        acc = fmaf(xv.y, wv.y, acc);
        acc = fmaf(xv.z, wv.z, acc);
        acc = fmaf(xv.w, wv.w, acc);
    }

    float* z   = ws + Z_OFF;
    float* src = ws + SRC_OFF;
    float* dst = ws + DST_OFF;
    z[(row0 + r) * ODIM + k] = acc;

    float sv = acc * a[k];
    float dv = acc * a[32 + k];
    #pragma unroll
    for (int off = 16; off >= 1; off >>= 1) {
        sv += __shfl_xor(sv, off, 32);
        dv += __shfl_xor(dv, off, 32);
    }
    if (k == 0) { src[row0 + r] = sv; dst[row0 + r] = dv; }
}

// Clenshaw evaluation of the Chebyshev interpolant
__device__ __forceinline__ float cheb_eval(const float cc[NCHEB + 1], float ts)
{
    float u  = fmaf(2.0f, ts, -1.0f);
    float tu = u + u;
    float b1 = 0.f, b2 = 0.f;
    #pragma unroll
    for (int k = NCHEB; k >= 1; --k) {
        float b = fmaf(tu, b1, cc[k] - b2);
        b2 = b1; b1 = b;
    }
    return fmaf(u, b1, cc[0] - b2);
}

// ---------------------------------------------------------------------------
// Kernel M: logits (in registers) -> softmax -> att@z + z -> LayerNorm.
// 4 rows per block, 512 blocks. LDS: p once-written/once-read + partials.
// ---------------------------------------------------------------------------
__global__ __launch_bounds__(256) void k_main(const int* __restrict__ adj,
                                              const float* __restrict__ tsm,
                                              const float* __restrict__ ws,
                                              const float* __restrict__ gam,
                                              const float* __restrict__ bet,
                                              float* __restrict__ out)
{
    __shared__ float lg[ROWS][NN];            // 32 KB: normalized probabilities
    __shared__ float zi[ROWS][ODIM];
    __shared__ float wredm[4][ROWS];
    __shared__ float wreds[4][ROWS];
    __shared__ float part[32][ROWS][ODIM];    // 16 KB

    const float* cw  = ws;
    const float* z   = ws + Z_OFF;
    const float* src = ws + SRC_OFF;
    const float* dst = ws + DST_OFF;

    const int tid  = threadIdx.x;
    const int row0 = blockIdx.x * ROWS;
    const int wid  = tid >> 6;

    float cc[NCHEB + 1];
    #pragma unroll
    for (int k = 0; k <= NCHEB; ++k) cc[k] = cw[k];

    if (tid < ROWS * ODIM) zi[tid >> 5][tid & 31] = z[row0 * ODIM + tid];

    float srcv[ROWS];
    #pragma unroll
    for (int r = 0; r < ROWS; ++r) srcv[r] = src[row0 + r];

    // ---- phase 1: logits into REGISTERS + per-thread row max --------------
    float ev[2][ROWS][4];
    float rmax[ROWS] = {NEGINF, NEGINF, NEGINF, NEGINF};

    #pragma unroll
    for (int jj = 0; jj < 2; ++jj) {
        const int j = jj * 1024 + tid * 4;
        float4 d4 = *reinterpret_cast<const float4*>(dst + j);
        const float dv[4] = {d4.x, d4.y, d4.z, d4.w};
        #pragma unroll
        for (int r = 0; r < ROWS; ++r) {
            const int base = (row0 + r) * NN + j;
            int4   a4 = *reinterpret_cast<const int4*>(adj + base);
            float4 t4 = *reinterpret_cast<const float4*>(tsm + base);
            const int   av[4] = {a4.x, a4.y, a4.z, a4.w};
            const float tv[4] = {t4.x, t4.y, t4.z, t4.w};
            #pragma unroll
            for (int q = 0; q < 4; ++q) {
                float e0 = srcv[r] + dv[q] + cheb_eval(cc, tv[q]);
                e0 = e0 > 0.f ? e0 : LEAK * e0;
                e0 = (av[q] > 0) ? e0 : NEGINF;
                ev[jj][r][q] = e0;
                rmax[r] = fmaxf(rmax[r], e0);
            }
        }
    }

    // ---- block max reduction ---------------------------------------------
    #pragma unroll
    for (int r = 0; r < ROWS; ++r) {
        float v = rmax[r];
        #pragma unroll
        for (int off = 32; off >= 1; off >>= 1) v = fmaxf(v, __shfl_xor(v, off, 64));
        if ((tid & 63) == 0) wredm[wid][r] = v;
    }
    __syncthreads();
    float m[ROWS];
    #pragma unroll
    for (int r = 0; r < ROWS; ++r)
        m[r] = fmaxf(fmaxf(wredm[0][r], wredm[1][r]), fmaxf(wredm[2][r], wredm[3][r]));

    // ---- exp in registers + row sums -------------------------------------
    float rs[ROWS] = {0.f, 0.f, 0.f, 0.f};
    #pragma unroll
    for (int jj = 0; jj < 2; ++jj)
        #pragma unroll
        for (int r = 0; r < ROWS; ++r)
            #pragma unroll
            for (int q = 0; q < 4; ++q) {
                float p = __expf(ev[jj][r][q] - m[r]);
                ev[jj][r][q] = p;
                rs[r] += p;
            }
    #pragma unroll
    for (int r = 0; r < ROWS; ++r) {
        float v = rs[r];
        #pragma unroll
        for (int off = 32; off >= 1; off >>= 1) v += __shfl_xor(v, off, 64);
        if ((tid & 63) == 0) wreds[wid][r] = v;
    }
    __syncthreads();
    float inv[ROWS];
    #pragma unroll
    for (int r = 0; r < ROWS; ++r)
        inv[r] = 1.0f / ((wreds[0][r] + wreds[1][r]) + (wreds[2][r] + wreds[3][r]));

    // ---- write NORMALIZED p to LDS (single write pass) --------------------
    #pragma unroll
    for (int jj = 0; jj < 2; ++jj) {
        const int j = jj * 1024 + tid * 4;
        #pragma unroll
        for (int r = 0; r < ROWS; ++r) {
            float4 v = make_float4(ev[jj][r][0] * inv[r], ev[jj][r][1] * inv[r],
                                   ev[jj][r][2] * inv[r], ev[jj][r][3] * inv[r]);
            *reinterpret_cast<float4*>(&lg[r][j]) = v;
        }
    }
    __syncthreads();

    // ---- phase 2: acc[r][k] = sum_j p[r][j] * z[j][k], float4 everywhere --
    const int kq = tid & 7, g = tid >> 3;          // k = 4*kq..4*kq+3, 32 j-groups
    const float4* z4 = reinterpret_cast<const float4*>(z);
    float4 acc[ROWS];
    #pragma unroll
    for (int r = 0; r < ROWS; ++r) acc[r] = make_float4(0.f, 0.f, 0.f, 0.f);

    #pragma unroll 2
    for (int jj = 0; jj < 16; ++jj) {
        const int j0 = jj * 128 + g * 4;           // 4 consecutive j per thread
        float4 p[ROWS];
        #pragma unroll
        for (int r = 0; r < ROWS; ++r)
            p[r] = *reinterpret_cast<const float4*>(&lg[r][j0]);
        #pragma unroll
        for (int i = 0; i < 4; ++i) {
            float4 zv = z4[(j0 + i) * (ODIM / 4) + kq];
            #pragma unroll
            for (int r = 0; r < ROWS; ++r) {
                const float pv = (i == 0) ? p[r].x : (i == 1) ? p[r].y
                               : (i == 2) ? p[r].z : p[r].w;
                acc[r].x = fmaf(pv, zv.x, acc[r].x);
                acc[r].y = fmaf(pv, zv.y, acc[r].y);
                acc[r].z = fmaf(pv, zv.z, acc[r].z);
                acc[r].w = fmaf(pv, zv.w, acc[r].w);
            }
        }
    }
    #pragma unroll
    for (int r = 0; r < ROWS; ++r)
        *reinterpret_cast<float4*>(&part[g][r][kq * 4]) = acc[r];
    __syncthreads();

    // ---- epilogue: temp = att@z + z, LayerNorm ----------------------------
    if (tid < ROWS * ODIM) {
        const int r = tid >> 5, kk = tid & 31;
        float tot = 0.f;
        #pragma unroll
        for (int gg = 0; gg < 32; ++gg) tot += part[gg][r][kk];
        float temp = tot + zi[r][kk];

        float mu = temp;
        #pragma unroll
        for (int off = 16; off >= 1; off >>= 1) mu += __shfl_xor(mu, off, 32);
        mu *= (1.0f / 32.0f);
        float d = temp - mu;
        float v2 = d * d;
        #pragma unroll
        for (int off = 16; off >= 1; off >>= 1) v2 += __shfl_xor(v2, off, 32);
        v2 *= (1.0f / 32.0f);
        float y = d * rsqrtf(v2 + LNEPS) * gam[kk] + bet[kk];
        out[(row0 + r) * ODIM + kk] = y;
    }
}

// ---------------------------------------------------------------------------
extern "C" void kernel_launch(void* const* d_in, const int* in_sizes, int n_in,
                              void* d_out, int out_size, void* d_ws, size_t ws_size,
                              hipStream_t stream)
{
    const float* ini = (const float*)d_in[0];
    const int*   adj = (const int*)  d_in[1];
    const float* tsm = (const float*)d_in[2];
    const float* a   = (const float*)d_in[3];
    const int*   te  = (const int*)  d_in[4];
    const float* W   = (const float*)d_in[5];
    const float* bfq = (const float*)d_in[6];
    const float* gam = (const float*)d_in[7];
    const float* bet = (const float*)d_in[8];
    float* ws  = (float*)d_ws;
    float* out = (float*)d_out;

    k_z<<<NN / 8, 256, 0, stream>>>(ini, a, W, bfq, te, ws);
    k_main<<<NN / ROWS, 256, 0, stream>>>(adj, tsm, ws, gam, bet, out);
}